// Round 9
// baseline (709.953 us; speedup 1.0000x reference)
//
#include <hip/hip_runtime.h>
#include <math.h>

#define B_ 2
#define S_ 512
#define P_ 64
#define T_ 576          // P_+S_
#define D_ 1024
#define L_ 4
#define DI_ 2048
#define DS_ 16
#define DC_ 4
#define DR_ 64
#define PCD_ 768
#define M_ (B_*T_)      // 1152
#define CCH 18          // scan chunk length (T_/CCH = 32 chunks)
#define NC (T_/CCH)     // 32 chunks -> NC*B*DI threads = 512 blocks
#define XKS 16          // x_proj K-splits (KC = 2048/16 = 128)
#define OPK 4           // out_proj K-splits

// per-layer small-weight cvt (x_proj + dt_proj only; in/out_proj weights are
// now consumed as fp32 directly by the GEMMs)
#define N_XP (96*DI_/4)
#define N_DTP (DI_*DR_/4)
#define CVB ((N_XP + N_DTP + 255) / 256)
#define SETSZ ((size_t)96*DI_ + DI_*DR_)

typedef __attribute__((ext_vector_type(8))) short bf16x8;
typedef __attribute__((ext_vector_type(4))) float f32x4;

__device__ __forceinline__ float silu_f(float v) { return v / (1.f + __expf(-v)); }
__device__ __forceinline__ float softplus_f(float v) {
    return fmaxf(v, 0.f) + log1pf(__expf(-fabsf(v)));
}
__device__ __forceinline__ unsigned short bf16_rne(float x) {
    unsigned int b = __float_as_uint(x);
    b += 0x7fffu + ((b >> 16) & 1u);
    return (unsigned short)(b >> 16);
}
__device__ __forceinline__ float bf16_to_f(unsigned short u) {
    return __uint_as_float((unsigned int)u << 16);
}

typedef const void __attribute__((address_space(1)))* gas_t;
typedef void __attribute__((address_space(3)))* las_t;
__device__ __forceinline__ void async16(const void* g, void* l) {
    __builtin_amdgcn_global_load_lds((gas_t)g, (las_t)l, 16, 0, 0);
}

// shared cvt tail: converts one 256-thread block's worth of fp32->bf16
__device__ __forceinline__ void cvt2_body(int i,
    const float* s0, unsigned short* d0, int n0,
    const float* s1, unsigned short* d1, int n1)
{
    const float* s; unsigned short* d; int off;
    if (i < n0)           { s = s0; d = d0; off = i; }
    else if (i < n0 + n1) { s = s1; d = d1; off = i - n0; }
    else return;
    const float4 v = ((const float4*)s)[off];
    ushort4 o;
    o.x = bf16_rne(v.x); o.y = bf16_rne(v.y);
    o.z = bf16_rne(v.z); o.w = bf16_rne(v.w);
    ((ushort4*)d)[off] = o;
}

// ---------------------------------------------------------------------------
// bf16 MFMA GEMM: C[m,n] (+)= sum_k A[m,k]*W[n,k]. Tile = 128 x BN (BN=64).
// 2-phase pipeline: LDS double-buffered, tile t+1 staged before tile t's
// compute, one barrier per K-step.
// WF32: B-operand is FP32 in global ([N][K] row-major, the RAW weight
// tensor). Reg-staged (2 x float4/thread), converted with the SAME bf16_rne
// used by the old cvt pass (bit-identical MFMA inputs), ds_written into the
// same LDS layout after the MFMA block (T14 issue-early/write-late: load
// latency hides under compute). Eliminates the 50MB/layer weight cvt pass.
// EPI: 6 = split-K fp32 partial store (prepend GEMMs, WF32=false);
//      7 = in_proj fused epilogue, bf16 outs: n<DI -> xb; n>=DI -> silu->szb;
//      8 = split-K BF16 partial store (out_proj).
// ---------------------------------------------------------------------------
template<int EPI, int BN, bool WF32>
__global__ __launch_bounds__(256) void gemm_mfma_kernel(
    const unsigned short* __restrict__ A, const void* __restrict__ Wv,
    float* __restrict__ C, float* __restrict__ C2,
    int M, int N, int K, int Kchunk)
{
    constexpr int NF = BN / 32;              // n-frags per wave (2 or 4)
    __shared__ unsigned short As[2][128 * 32];
    __shared__ unsigned short Bs[2][BN * 32];
    const int tid = threadIdx.x;
    const int wave = tid >> 6;
    const int lane = tid & 63;
    const int m0 = blockIdx.y * 128, n0 = blockIdx.x * BN;
    const int kbase = blockIdx.z * Kchunk;
    const int wm = (wave >> 1) * 64, wn = (wave & 1) * (BN / 2);

    const int srow = (wave << 5) + (lane >> 2);
    const int selem = (lane & 3) * 8;
    const unsigned short* gA = A + (size_t)(m0 + srow) * K + kbase + selem;
    const unsigned short* gB16 = WF32 ? nullptr :
        (const unsigned short*)Wv + (size_t)(n0 + srow) * K + kbase + selem;
    // fp32-weight staging addressing (BN=64: 256 thr = 64 rows x 8 k-elems)
    const int brow = tid >> 2;
    const int bke  = (tid & 3) * 8;
    const float* gBw = WF32 ?
        (const float*)Wv + (size_t)(n0 + brow) * K + kbase + bke : nullptr;
    const int lofs = (wave << 5) * 32;

    f32x4 acc[4][NF];
    #pragma unroll
    for (int i = 0; i < 4; ++i)
        #pragma unroll
        for (int j = 0; j < NF; ++j)
            acc[i][j] = (f32x4){0.f, 0.f, 0.f, 0.f};

    const int fr = lane & 15;
    const int fq = lane >> 4;
    const int aoff = (wm + fr) * 32 + fq * 8;
    const int boff = (wn + fr) * 32 + fq * 8;

    const int NT = Kchunk >> 5;              // 32-wide K steps

    #define STAGE_A(b, t) do {                                            \
        const unsigned short* pA = gA + (t) * 32;                         \
        async16(pA, &As[b][lofs]);                                        \
        async16(pA + (size_t)16 * K, &As[b][lofs + 16 * 32]);             \
    } while (0)
    #define STAGE_B16(b, t) do {                                          \
        if (wave < BN / 32) {                                             \
            const unsigned short* pB = gB16 + (t) * 32;                   \
            async16(pB, &Bs[b][lofs]);                                    \
            async16(pB + (size_t)16 * K, &Bs[b][lofs + 16 * 32]);         \
        }                                                                 \
    } while (0)
    #define BW_WRITE(b) do {                                              \
        bf16x8 pk;                                                        \
        pk[0] = (short)bf16_rne(b0.x); pk[1] = (short)bf16_rne(b0.y);     \
        pk[2] = (short)bf16_rne(b0.z); pk[3] = (short)bf16_rne(b0.w);     \
        pk[4] = (short)bf16_rne(b1.x); pk[5] = (short)bf16_rne(b1.y);     \
        pk[6] = (short)bf16_rne(b1.z); pk[7] = (short)bf16_rne(b1.w);     \
        *(bf16x8*)&Bs[b][brow * 32 + bke] = pk;                           \
    } while (0)

    float4 b0, b1;
    if (WF32) { b0 = *(const float4*)gBw; b1 = *(const float4*)(gBw + 4); }
    STAGE_A(0, 0);
    if (!WF32) STAGE_B16(0, 0);
    if (WF32) BW_WRITE(0);
    __syncthreads();                         // buf0 ready
    for (int t = 0; t < NT; ++t) {
        const int cur = t & 1;
        if (t + 1 < NT) {
            if (WF32) {
                b0 = *(const float4*)(gBw + (size_t)(t + 1) * 32);
                b1 = *(const float4*)(gBw + (size_t)(t + 1) * 32 + 4);
            }
            STAGE_A(cur ^ 1, t + 1);
            if (!WF32) STAGE_B16(cur ^ 1, t + 1);
        }
        bf16x8 af[4], bf[NF];
        #pragma unroll
        for (int i = 0; i < 4; ++i) af[i] = *(const bf16x8*)&As[cur][aoff + i * 512];
        #pragma unroll
        for (int j = 0; j < NF; ++j) bf[j] = *(const bf16x8*)&Bs[cur][boff + j * 512];
        #pragma unroll
        for (int i = 0; i < 4; ++i)
            #pragma unroll
            for (int j = 0; j < NF; ++j)
                acc[i][j] = __builtin_amdgcn_mfma_f32_16x16x32_bf16(
                    af[i], bf[j], acc[i][j], 0, 0, 0);
        if (WF32 && t + 1 < NT) BW_WRITE(cur ^ 1);   // write-late: after MFMA
        __syncthreads();
    }
    #undef STAGE_A
    #undef STAGE_B16
    #undef BW_WRITE

    // C/D layout (m89-verified): col = lane&15, row = (lane>>4)*4 + reg
    #pragma unroll
    for (int i = 0; i < 4; ++i) {
        const int m = m0 + wm + i * 16 + fq * 4;
        #pragma unroll
        for (int j = 0; j < NF; ++j) {
            const int n = n0 + wn + j * 16 + fr;
            if (EPI == 6) {
                float* p = C + ((size_t)blockIdx.z * M + m) * N + n;
                #pragma unroll
                for (int r = 0; r < 4; ++r)
                    p[(size_t)r * N] = acc[i][j][r];
            } else if (EPI == 8) {
                unsigned short* p = (unsigned short*)C +
                                    ((size_t)blockIdx.z * M + m) * N + n;
                #pragma unroll
                for (int r = 0; r < 4; ++r)
                    p[(size_t)r * N] = bf16_rne(acc[i][j][r]);
            } else if (EPI == 7) {
                if (n < DI_) {
                    unsigned short* p = (unsigned short*)C + (size_t)m * DI_ + n;
                    #pragma unroll
                    for (int r = 0; r < 4; ++r)
                        p[(size_t)r * DI_] = bf16_rne(acc[i][j][r]);
                } else {
                    unsigned short* p = (unsigned short*)C2 + (size_t)m * DI_ + (n - DI_);
                    #pragma unroll
                    for (int r = 0; r < 4; ++r)
                        p[(size_t)r * DI_] = bf16_rne(silu_f(acc[i][j][r]));
                }
            }
        }
    }
}

// ---------------------------------------------------------------------------
// x_proj split-K MFMA (2-phase pipelined):
// P[ks][m][96] = xi_bf[m, ks*128:(ks+1)*128] @ W[96, ...]^T
// ---------------------------------------------------------------------------
__global__ __launch_bounds__(256) void xproj_mfma_kernel(
    const unsigned short* __restrict__ A,   // [M, 2048] bf16
    const unsigned short* __restrict__ W,   // [96, 2048] bf16
    float* __restrict__ P)                  // [XKS, M, 96]
{
    __shared__ unsigned short As[2][128 * 32];
    __shared__ unsigned short Bs[2][96 * 32];
    const int tid = threadIdx.x;
    const int wave = tid >> 6;
    const int lane = tid & 63;
    const int m0 = blockIdx.y * 128;
    const int kbase = blockIdx.x * (DI_ / XKS);   // 128
    const int wm = (wave >> 1) * 64, wn = (wave & 1) * 48;

    const int srow = (wave << 5) + (lane >> 2);
    const int selem = (lane & 3) * 8;
    const unsigned short* gA = A + (size_t)(m0 + srow) * DI_ + kbase + selem;
    const unsigned short* gB = W + (size_t)srow * DI_ + kbase + selem;
    const int lofs = (wave << 5) * 32;

    f32x4 acc[4][3];
    #pragma unroll
    for (int i = 0; i < 4; ++i)
        #pragma unroll
        for (int j = 0; j < 3; ++j)
            acc[i][j] = (f32x4){0.f, 0.f, 0.f, 0.f};

    const int fr = lane & 15;
    const int fq = lane >> 4;
    const int aoff = (wm + fr) * 32 + fq * 8;
    const int boff = (wn + fr) * 32 + fq * 8;

    #define XSTAGE(b, t) do {                                             \
        const unsigned short* pA = gA + (t) * 32;                         \
        async16(pA, &As[b][lofs]);                                        \
        async16(pA + (size_t)16 * DI_, &As[b][lofs + 16 * 32]);           \
        if (wave < 3) {                                                   \
            const unsigned short* pB = gB + (t) * 32;                     \
            async16(pB, &Bs[b][lofs]);                                    \
            async16(pB + (size_t)16 * DI_, &Bs[b][lofs + 16 * 32]);       \
        }                                                                 \
    } while (0)

    XSTAGE(0, 0);
    __syncthreads();
    #pragma unroll
    for (int t = 0; t < 4; ++t) {
        const int cur = t & 1;
        if (t + 1 < 4) XSTAGE(cur ^ 1, t + 1);
        bf16x8 af[4], bf[3];
        #pragma unroll
        for (int i = 0; i < 4; ++i) af[i] = *(const bf16x8*)&As[cur][aoff + i * 512];
        #pragma unroll
        for (int j = 0; j < 3; ++j) bf[j] = *(const bf16x8*)&Bs[cur][boff + j * 512];
        #pragma unroll
        for (int i = 0; i < 4; ++i)
            #pragma unroll
            for (int j = 0; j < 3; ++j)
                acc[i][j] = __builtin_amdgcn_mfma_f32_16x16x32_bf16(
                    af[i], bf[j], acc[i][j], 0, 0, 0);
        __syncthreads();
    }
    #undef XSTAGE

    float* Pb = P + ((size_t)blockIdx.x * M_ + m0) * 96;
    #pragma unroll
    for (int i = 0; i < 4; ++i) {
        const int m = wm + i * 16 + fq * 4;
        #pragma unroll
        for (int j = 0; j < 3; ++j) {
            const int n = wn + j * 16 + fr;
            #pragma unroll
            for (int r = 0; r < 4; ++r)
                Pb[(size_t)(m + r) * 96 + n] = acc[i][j][r];
        }
    }
}

// reduce partials; emit dtr_bf [m][64] plus per-row scan streams
// Bc[m][16], Cc[m][16] (contiguous states per timestep).
__global__ __launch_bounds__(256) void xproj_reduce_kernel(
    const float* __restrict__ P, float* __restrict__ Bc, float* __restrict__ Cc,
    unsigned short* __restrict__ dtr_bf)
{
    const int i = blockIdx.x * 256 + threadIdx.x;
    if (i >= M_ * 96) return;
    float s = 0.f;
    #pragma unroll
    for (int ks = 0; ks < XKS; ++ks) s += P[(size_t)ks * (M_ * 96) + i];
    const int m = i / 96;
    const int n = i - m * 96;
    if (n < DR_)            dtr_bf[(size_t)m * DR_ + n] = bf16_rne(s);
    else if (n < DR_ + DS_) Bc[(size_t)m * DS_ + (n - DR_)] = s;
    else                    Cc[(size_t)m * DS_ + (n - DR_ - DS_)] = s;
}

// ---------------------------------------------------------------------------
// Merged prepend-phase conversions: pc fp32->bf16 (blocks 0..95), w1
// transpose (96..287), w2 transpose (288..543). Block-uniform branches.
// ---------------------------------------------------------------------------
__global__ __launch_bounds__(256) void prep_cvt_kernel(
    const float* __restrict__ pc, unsigned short* __restrict__ pcb,
    const float* __restrict__ w1, unsigned short* __restrict__ w1t,
    const float* __restrict__ w2, unsigned short* __restrict__ w2t)
{
    __shared__ float t[64][65];
    const int bid = blockIdx.x;
    const int tx = threadIdx.x & 63;
    const int ty = threadIdx.x >> 6;
    if (bid < 96) {
        const int i = bid * 256 + threadIdx.x;
        const float4 v = ((const float4*)pc)[i];
        ushort4 o;
        o.x = bf16_rne(v.x); o.y = bf16_rne(v.y);
        o.z = bf16_rne(v.z); o.w = bf16_rne(v.w);
        ((ushort4*)pcb)[i] = o;
        return;
    }
    const float* in; unsigned short* outp; int K, N, k0, n0;
    if (bid < 96 + 192) {
        const int b = bid - 96;
        K = PCD_; N = D_; in = w1; outp = w1t;
        k0 = (b % (PCD_ / 64)) * 64; n0 = (b / (PCD_ / 64)) * 64;
    } else {
        const int b = bid - 288;
        K = D_; N = D_; in = w2; outp = w2t;
        k0 = (b % (D_ / 64)) * 64; n0 = (b / (D_ / 64)) * 64;
    }
    #pragma unroll
    for (int j = 0; j < 16; ++j) {
        const int kk = ty * 16 + j;
        t[kk][tx] = in[(size_t)(k0 + kk) * N + n0 + tx];
    }
    __syncthreads();
    #pragma unroll
    for (int j = 0; j < 16; ++j) {
        const int nn = ty * 16 + j;
        outp[(size_t)(n0 + nn) * K + k0 + tx] = bf16_rne(t[tx][nn]);
    }
}

// generalized split-K reduces (stride MN between partials)
__global__ __launch_bounds__(256) void reduce_silu_bf16_kernel(
    const float* __restrict__ P, unsigned short* __restrict__ o, int MN, int ns)
{
    const int i = blockIdx.x * 256 + threadIdx.x;
    if (i >= MN) return;
    float s = 0.f;
    for (int k = 0; k < ns; ++k) s += P[(size_t)k * MN + i];
    o[i] = bf16_rne(silu_f(s));
}
__global__ __launch_bounds__(256) void reduce_fp32_kernel(
    const float* __restrict__ P, float* __restrict__ o, int MN, int ns)
{
    const int i = blockIdx.x * 256 + threadIdx.x;
    if (i >= MN) return;
    float s = 0.f;
    for (int k = 0; k < ns; ++k) s += P[(size_t)k * MN + i];
    o[i] = s;
}

// out_proj split-K reduce (BF16 partials) + residual add into h + (optional)
// next layer's rmsnorm->bf16, PLUS (blocks >= M_) next layer's small-weight
// cvt (x_proj + dt_proj only; 320 blocks).
__global__ __launch_bounds__(256) void outproj_rmsnorm_cvt_kernel(
    const unsigned short* __restrict__ P, float* __restrict__ h,
    const float* __restrict__ w, unsigned short* __restrict__ outb, int donorm,
    const float* s0, unsigned short* d0, int n0,
    const float* s1, unsigned short* d1, int n1)
{
    const int bid = blockIdx.x;
    if (bid >= M_) {
        cvt2_body((bid - M_) * 256 + threadIdx.x, s0, d0, n0, s1, d1, n1);
        return;
    }
    const int r = bid;
    const int i = r * 256 + threadIdx.x;        // float4/ushort4 col index
    float4 v = ((float4*)h)[i];
    #pragma unroll
    for (int k = 0; k < OPK; ++k) {
        const ushort4 a4 = ((const ushort4*)P)[(size_t)k * (M_ * D_ / 4) + i];
        v.x += bf16_to_f(a4.x); v.y += bf16_to_f(a4.y);
        v.z += bf16_to_f(a4.z); v.w += bf16_to_f(a4.w);
    }
    ((float4*)h)[i] = v;
    if (!donorm) return;
    float ss = v.x * v.x + v.y * v.y + v.z * v.z + v.w * v.w;
    ss += __shfl_xor(ss, 32, 64);
    ss += __shfl_xor(ss, 16, 64);
    ss += __shfl_xor(ss, 8, 64);
    ss += __shfl_xor(ss, 4, 64);
    ss += __shfl_xor(ss, 2, 64);
    ss += __shfl_xor(ss, 1, 64);
    __shared__ float red[4];
    if ((threadIdx.x & 63) == 0) red[threadIdx.x >> 6] = ss;
    __syncthreads();
    const float tot = red[0] + red[1] + red[2] + red[3];
    const float scale = rsqrtf(tot * (1.f / D_) + 1e-5f);
    const float4 wv = ((const float4*)w)[threadIdx.x];
    ushort4 o;
    o.x = bf16_rne(v.x * scale * wv.x);
    o.y = bf16_rne(v.y * scale * wv.y);
    o.z = bf16_rne(v.z * scale * wv.z);
    o.w = bf16_rne(v.w * scale * wv.w);
    ((ushort4*)(outb + (size_t)r * D_))[threadIdx.x] = o;
}

// h[b*T+t, :] = (t < P) ? p[b*P+t, :] : x[b*S + (t-P), :]
__global__ __launch_bounds__(256) void assemble_h_kernel(
    const float* __restrict__ p, const float* __restrict__ x, float* __restrict__ h)
{
    const int idx = blockIdx.x * 256 + threadIdx.x;
    const int r = idx >> 8;
    const int c = idx & 255;
    const int b = r / T_;
    const int t = r - b * T_;
    float4 v;
    if (t < P_) v = ((const float4*)p)[(size_t)(b * P_ + t) * 256 + c];
    else        v = ((const float4*)x)[(size_t)(b * S_ + (t - P_)) * 256 + c];
    ((float4*)h)[idx] = v;
}

// rmsnorm -> bf16 (feeds in_proj MFMA) + (blocks >= M_) layer-0 small cvt.
__global__ __launch_bounds__(256) void rmsnorm_cvt_kernel(
    const float* __restrict__ x, const float* __restrict__ w,
    unsigned short* __restrict__ outb,
    const float* s0, unsigned short* d0, int n0,
    const float* s1, unsigned short* d1, int n1)
{
    const int bid = blockIdx.x;
    if (bid >= M_) {
        cvt2_body((bid - M_) * 256 + threadIdx.x, s0, d0, n0, s1, d1, n1);
        return;
    }
    const int r = bid;
    const float4 v = ((const float4*)(x + (size_t)r * D_))[threadIdx.x];
    float ss = v.x * v.x + v.y * v.y + v.z * v.z + v.w * v.w;
    ss += __shfl_xor(ss, 32, 64);
    ss += __shfl_xor(ss, 16, 64);
    ss += __shfl_xor(ss, 8, 64);
    ss += __shfl_xor(ss, 4, 64);
    ss += __shfl_xor(ss, 2, 64);
    ss += __shfl_xor(ss, 1, 64);
    __shared__ float red[4];
    if ((threadIdx.x & 63) == 0) red[threadIdx.x >> 6] = ss;
    __syncthreads();
    const float tot = red[0] + red[1] + red[2] + red[3];
    const float scale = rsqrtf(tot * (1.f / D_) + 1e-5f);
    const float4 wv = ((const float4*)w)[threadIdx.x];
    ushort4 o;
    o.x = bf16_rne(v.x * scale * wv.x);
    o.y = bf16_rne(v.y * scale * wv.y);
    o.z = bf16_rne(v.z * scale * wv.z);
    o.w = bf16_rne(v.w * scale * wv.w);
    ((ushort4*)(outb + (size_t)r * D_))[threadIdx.x] = o;
}

// final rmsnorm (fp32 out): rows over B*S; reads h[b*T+P+s]
__global__ __launch_bounds__(256) void final_rmsnorm_kernel(
    const float* __restrict__ h, const float* __restrict__ w, float* __restrict__ out)
{
    const int r = blockIdx.x;
    const int b = r / S_;
    const int s = r - b * S_;
    const int hr = b * T_ + P_ + s;
    const float4 v = ((const float4*)(h + (size_t)hr * D_))[threadIdx.x];
    float ss = v.x * v.x + v.y * v.y + v.z * v.z + v.w * v.w;
    ss += __shfl_xor(ss, 32, 64);
    ss += __shfl_xor(ss, 16, 64);
    ss += __shfl_xor(ss, 8, 64);
    ss += __shfl_xor(ss, 4, 64);
    ss += __shfl_xor(ss, 2, 64);
    ss += __shfl_xor(ss, 1, 64);
    __shared__ float red[4];
    if ((threadIdx.x & 63) == 0) red[threadIdx.x >> 6] = ss;
    __syncthreads();
    const float tot = red[0] + red[1] + red[2] + red[3];
    const float scale = rsqrtf(tot * (1.f / D_) + 1e-5f);
    const float4 wv = ((const float4*)w)[threadIdx.x];
    float4 o;
    o.x = v.x * scale * wv.x; o.y = v.y * scale * wv.y;
    o.z = v.z * scale * wv.z; o.w = v.w * scale * wv.w;
    ((float4*)(out + (size_t)r * D_))[threadIdx.x] = o;
}

// ---------------------------------------------------------------------------
// Fused causal depthwise conv (DC=4) + bias + silu. Reads compact bf16 xb,
// emits xi as bf16 [m][e] (sole copy).
// ---------------------------------------------------------------------------
__global__ __launch_bounds__(256) void conv_silu_kernel(
    const unsigned short* __restrict__ xb, const float* __restrict__ cw,
    const float* __restrict__ cb, unsigned short* __restrict__ xib)
{
    __shared__ float xs[67][64];    // rows r0-3 .. r0+63
    const int tid = threadIdx.x;
    const int tx = tid & 63;
    const int ty = tid >> 6;        // 0..3
    const int r0 = blockIdx.x * 64;
    const int e0 = blockIdx.y * 64;
    const int bt0 = (r0 / T_) * T_; // batch start row

    for (int j = ty; j < 67; j += 4) {
        const int r = r0 + j - 3;
        xs[j][tx] = (r >= bt0) ? bf16_to_f(xb[(size_t)r * DI_ + e0 + tx]) : 0.f;
    }
    __syncthreads();
    const float4 w = *(const float4*)(cw + (size_t)(e0 + tx) * 4);
    const float bias = cb[e0 + tx];
    #pragma unroll
    for (int j = 0; j < 16; ++j) {
        const int rl = ty * 16 + j;
        float v = bias;
        v = fmaf(w.x, xs[rl + 0][tx], v);   // x[r-3]
        v = fmaf(w.y, xs[rl + 1][tx], v);   // x[r-2]
        v = fmaf(w.z, xs[rl + 2][tx], v);   // x[r-1]
        v = fmaf(w.w, xs[rl + 3][tx], v);   // x[r]
        xib[(size_t)(r0 + rl) * DI_ + e0 + tx] = bf16_rne(silu_f(v));
    }
}

// ---------------------------------------------------------------------------
// Chunked selective scan with FUSED dt_proj (3 plain-stream kernels; kernel
// boundaries provide cross-XCD coherence — the cooperative fusion raced).
// dt recomputed in scan1 and scan3 with identical op order.
// ---------------------------------------------------------------------------
__global__ __launch_bounds__(256) void scan_chunk1_kernel(
    const unsigned short* __restrict__ dtr,   // [M, 64] bf16
    const unsigned short* __restrict__ dtw,   // [DI, 64] bf16
    const float* __restrict__ dtbias,         // [DI]
    const float* __restrict__ Bc,             // [M, DS]
    const unsigned short* __restrict__ xib,   // [M, DI] bf16
    const float* __restrict__ A_log,
    float* __restrict__ Ap, float* __restrict__ Hp)
{
    __shared__ float4 Bs[CCH][4];
    __shared__ float dtrs[CCH][DR_];          // 4.6KB, broadcast reads
    const int tid = threadIdx.x;
    const int e = ((blockIdx.x & 7) << 8) + tid;   // DI/256 = 8 blocks per (c,b)
    const int cb = blockIdx.x >> 3;                // c*B + b
    const int b = cb & (B_ - 1);
    const int c = cb >> 1;
    const int r0 = b * T_ + c * CCH;
    for (int i = tid; i < CCH * DS_; i += 256)
        ((float*)Bs)[i] = Bc[(size_t)r0 * DS_ + i];
    for (int i = tid; i < CCH * DR_ / 4; i += 256) {
        const ushort4 v4 = ((const ushort4*)(dtr + (size_t)r0 * DR_))[i];
        float* d = &dtrs[0][0] + i * 4;
        d[0] = bf16_to_f(v4.x); d[1] = bf16_to_f(v4.y);
        d[2] = bf16_to_f(v4.z); d[3] = bf16_to_f(v4.w);
    }
    float A2[DS_], h[DS_], a[DS_];
    const float* Ae = A_log + (size_t)e * DS_;
    #pragma unroll
    for (int s = 0; s < DS_; ++s) {
        A2[s] = -__expf(Ae[s]) * 1.44269504f;   // pre-scale for exp2
        h[s] = 0.f; a[s] = 1.f;
    }
    __syncthreads();
    // fused dt_proj for this thread's channel e
    float dt[CCH];
    {
        float w[DR_];
        const ushort4* wp = (const ushort4*)(dtw + (size_t)e * DR_);
        #pragma unroll
        for (int q = 0; q < 16; ++q) {
            const ushort4 v = wp[q];
            w[q * 4 + 0] = bf16_to_f(v.x);
            w[q * 4 + 1] = bf16_to_f(v.y);
            w[q * 4 + 2] = bf16_to_f(v.z);
            w[q * 4 + 3] = bf16_to_f(v.w);
        }
        const float bb = dtbias[e];
        #pragma unroll
        for (int t = 0; t < CCH; ++t) {
            float acc = 0.f;
            #pragma unroll
            for (int r = 0; r < DR_; ++r) acc = fmaf(dtrs[t][r], w[r], acc);
            dt[t] = softplus_f(acc + bb);
        }
    }
    const unsigned short* up = xib + (size_t)r0 * DI_ + e;
    #pragma unroll
    for (int t = 0; t < CCH; ++t) {
        const float dtv = dt[t];
        const float dtu = dtv * bf16_to_f(up[(size_t)t * DI_]);
        #pragma unroll
        for (int q = 0; q < 4; ++q) {
            const float4 bq = Bs[t][q];
            const float* bb = &bq.x;
            #pragma unroll
            for (int j = 0; j < 4; ++j) {
                const int s = q * 4 + j;
                const float da = __builtin_amdgcn_exp2f(dtv * A2[s]);
                a[s] *= da;
                h[s] = fmaf(da, h[s], bb[j] * dtu);
            }
        }
    }
    // layout [c][b][s][e]: every store coalesced across lanes
    const size_t o = (size_t)cb * DS_ * DI_ + e;
    #pragma unroll
    for (int s = 0; s < DS_; ++s) {
        Ap[o + (size_t)s * DI_] = a[s];
        Hp[o + (size_t)s * DI_] = h[s];
    }
}

__global__ __launch_bounds__(256) void scan_chunk2_kernel(
    float* __restrict__ Ap, float* __restrict__ Hp)
{
    const int g = blockIdx.x * 256 + threadIdx.x;
    float h = 0.f;
    #pragma unroll
    for (int c = 0; c < NC; ++c) {
        const size_t o = (size_t)c * (B_ * DI_ * DS_) + g;
        const float ap = Ap[o];
        const float hp = Hp[o];
        Hp[o] = h;
        h = fmaf(ap, h, hp);
    }
}

__global__ __launch_bounds__(256) void scan_chunk3_kernel(
    const unsigned short* __restrict__ dtr,   // [M, 64] bf16
    const unsigned short* __restrict__ dtw,   // [DI, 64] bf16
    const float* __restrict__ dtbias,         // [DI]
    const float* __restrict__ Bc,             // [M, DS]
    const float* __restrict__ Cc,             // [M, DS]
    const unsigned short* __restrict__ xib,   // [M, DI] bf16
    const unsigned short* __restrict__ szb,   // [M, DI] bf16 silu(z)
    const float* __restrict__ A_log, const float* __restrict__ Dp,
    const float* __restrict__ Hin, unsigned short* __restrict__ y)
{
    __shared__ float4 Bs[CCH][4], Cs[CCH][4];
    __shared__ float dtrs[CCH][DR_];
    const int tid = threadIdx.x;
    const int e = ((blockIdx.x & 7) << 8) + tid;
    const int cb = blockIdx.x >> 3;
    const int b = cb & (B_ - 1);
    const int c = cb >> 1;
    const int r0 = b * T_ + c * CCH;
    for (int i = tid; i < CCH * DS_; i += 256) {
        ((float*)Bs)[i] = Bc[(size_t)r0 * DS_ + i];
        ((float*)Cs)[i] = Cc[(size_t)r0 * DS_ + i];
    }
    for (int i = tid; i < CCH * DR_ / 4; i += 256) {
        const ushort4 v4 = ((const ushort4*)(dtr + (size_t)r0 * DR_))[i];
        float* d = &dtrs[0][0] + i * 4;
        d[0] = bf16_to_f(v4.x); d[1] = bf16_to_f(v4.y);
        d[2] = bf16_to_f(v4.z); d[3] = bf16_to_f(v4.w);
    }
    float A2[DS_], h[DS_];
    const float* Ae = A_log + (size_t)e * DS_;
    const float dpe = Dp[e];
    const size_t ho = (size_t)cb * DS_ * DI_ + e;
    #pragma unroll
    for (int s = 0; s < DS_; ++s) {
        A2[s] = -__expf(Ae[s]) * 1.44269504f;
        h[s] = Hin[ho + (size_t)s * DI_];
    }
    __syncthreads();
    // fused dt_proj (identical op order to scan1 -> identical dt values)
    float dt[CCH];
    {
        float w[DR_];
        const ushort4* wp = (const ushort4*)(dtw + (size_t)e * DR_);
        #pragma unroll
        for (int q = 0; q < 16; ++q) {
            const ushort4 v = wp[q];
            w[q * 4 + 0] = bf16_to_f(v.x);
            w[q * 4 + 1] = bf16_to_f(v.y);
            w[q * 4 + 2] = bf16_to_f(v.z);
            w[q * 4 + 3] = bf16_to_f(v.w);
        }
        const float bb = dtbias[e];
        #pragma unroll
        for (int t = 0; t < CCH; ++t) {
            float acc = 0.f;
            #pragma unroll
            for (int r = 0; r < DR_; ++r) acc = fmaf(dtrs[t][r], w[r], acc);
            dt[t] = softplus_f(acc + bb);
        }
    }
    const unsigned short* up = xib + (size_t)r0 * DI_ + e;
    const unsigned short* sp = szb + (size_t)r0 * DI_ + e;
    unsigned short* yp = y + (size_t)r0 * DI_ + e;
    #pragma unroll
    for (int t = 0; t < CCH; ++t) {
        const float dtv = dt[t];
        const float u   = bf16_to_f(up[(size_t)t * DI_]);
        const float dtu = dtv * u;
        float y0 = 0.f, y1 = 0.f, y2 = 0.f, y3 = 0.f;
        #pragma unroll
        for (int q = 0; q < 4; ++q) {
            const float4 bq = Bs[t][q];
            const float4 cq = Cs[t][q];
            const float* bb = &bq.x;
            const float* cc = &cq.x;
            #pragma unroll
            for (int j = 0; j < 4; ++j) {
                const int s = q * 4 + j;
                const float da = __builtin_amdgcn_exp2f(dtv * A2[s]);
                h[s] = fmaf(da, h[s], bb[j] * dtu);
                if (j == 0)      y0 = fmaf(h[s], cc[j], y0);
                else if (j == 1) y1 = fmaf(h[s], cc[j], y1);
                else if (j == 2) y2 = fmaf(h[s], cc[j], y2);
                else             y3 = fmaf(h[s], cc[j], y3);
            }
        }
        const float ysum = (y0 + y1) + (y2 + y3);
        const float yv = fmaf(u, dpe, ysum) * bf16_to_f(sp[(size_t)t * DI_]);
        yp[(size_t)t * DI_] = bf16_rne(yv);
    }
}

extern "C" void kernel_launch(void* const* d_in, const int* in_sizes, int n_in,
                              void* d_out, int out_size, void* d_ws, size_t ws_size,
                              hipStream_t stream)
{
    const float* x       = (const float*)d_in[0];
    const float* pc      = (const float*)d_in[1];
    const float* pre_w1  = (const float*)d_in[2];
    const float* pre_w2  = (const float*)d_in[3];
    const float* norm_w  = (const float*)d_in[4];
    const float* ip_w    = (const float*)d_in[5];
    const float* conv_w  = (const float*)d_in[6];
    const float* conv_b  = (const float*)d_in[7];
    const float* xp_w    = (const float*)d_in[8];
    const float* dtp_w   = (const float*)d_in[9];
    const float* dtp_b   = (const float*)d_in[10];
    const float* A_log   = (const float*)d_in[11];
    const float* D_param = (const float*)d_in[12];
    const float* op_w    = (const float*)d_in[13];
    const float* fnw     = (const float*)d_in[14];
    float* out = (float*)d_out;

    float* ws = (float*)d_ws;
    float* h    = ws;  ws += (size_t)M_ * D_;            // fp32 residual
    float* xz   = ws;  ws += (size_t)M_ * 2 * DI_;       // scan partials / Pop
    float* scr  = ws;  ws += (size_t)M_ * DI_;           // prepend GEMM2 partials
    float* Pbuf = ws;  ws += (size_t)XKS * M_ * 96;      // x_proj / prepend partials
    float* Bc   = ws;  ws += (size_t)DS_ * M_;           // B stream [m][s]
    float* Cc   = ws;  ws += (size_t)DS_ * M_;           // C stream [m][s]
    unsigned short* xn_bf  = (unsigned short*)ws;  ws += (size_t)M_ * D_ / 2;
    unsigned short* yb_bf  = (unsigned short*)ws;  ws += (size_t)M_ * DI_ / 2;
    unsigned short* xi_bf  = (unsigned short*)ws;  ws += (size_t)M_ * DI_ / 2;
    unsigned short* xb_bf  = (unsigned short*)ws;  ws += (size_t)M_ * DI_ / 2;
    unsigned short* szb_bf = (unsigned short*)ws;  ws += (size_t)M_ * DI_ / 2;
    unsigned short* dtr_bf = (unsigned short*)ws;  ws += (size_t)M_ * DR_ / 2;
    unsigned short* wsets  = (unsigned short*)ws;  ws += SETSZ;   // set 0 + set 1
    ws += SETSZ;
    unsigned short* pw_bf  = (unsigned short*)ws;  ws += ((size_t)PCD_ * D_ + (size_t)D_ * D_ + 1) / 2;

    // per-set small-weight pointers (double-buffered)
    unsigned short* xpw_b[2], *dtpw_b[2];
    for (int s = 0; s < 2; ++s) {
        unsigned short* base = wsets + (size_t)s * SETSZ;
        xpw_b[s]  = base;
        dtpw_b[s] = base + (size_t)96 * DI_;
    }

    // scan chunk partials alias xz: NC*B*DI*DS = 2.097M floats each.
    float* Ap = xz;
    float* Hp = xz + (size_t)NC * B_ * DI_ * DS_;

    // prepend-phase aliases (dead once the layer loop starts):
    unsigned short* pc_bf   = xi_bf;
    unsigned short* w1t_bf  = pw_bf;                    // [1024][768]
    unsigned short* w2t_bf  = pw_bf + (size_t)D_ * PCD_;// [1024][1024]
    unsigned short* tmp1_bf = xn_bf;
    float*          tmp2    = Pbuf;   // GEMM1 partials dead by then
    float*          P2buf   = scr;    // 16*131072 floats <= 2.36M
    // out_proj bf16 partials alias xz: OPK*M*D shorts = 9.4MB << xz
    unsigned short* Pop     = (unsigned short*)xz;

    const dim3 blk(256);

    // ---- prepend embed (MFMA path): silu(pc @ w1) @ w2 ----
    prep_cvt_kernel<<<dim3(96 + 192 + 256), blk, 0, stream>>>(
        pc, pc_bf, pre_w1, w1t_bf, pre_w2, w2t_bf);
    // GEMM1: [128, 1024, K=768], split-K 12 (192 blocks), silu-reduce -> bf16
    gemm_mfma_kernel<6, 64, false><<<dim3(D_ / 64, 1, 12), blk, 0, stream>>>(
        pc_bf, w1t_bf, Pbuf, nullptr, B_ * P_, D_, PCD_, PCD_ / 12);
    reduce_silu_bf16_kernel<<<dim3(B_ * P_ * D_ / 256), blk, 0, stream>>>(
        Pbuf, tmp1_bf, B_ * P_ * D_, 12);
    // GEMM2: [128, 1024, K=1024], split-K 16 (256 blocks), reduce -> fp32
    gemm_mfma_kernel<6, 64, false><<<dim3(D_ / 64, 1, 16), blk, 0, stream>>>(
        tmp1_bf, w2t_bf, P2buf, nullptr, B_ * P_, D_, D_, D_ / 16);
    reduce_fp32_kernel<<<dim3(B_ * P_ * D_ / 256), blk, 0, stream>>>(
        P2buf, tmp2, B_ * P_ * D_, 16);
    assemble_h_kernel<<<dim3(M_ * D_ / 4 / 256), blk, 0, stream>>>(tmp2, x, h);

    // first layer's rmsnorm + layer-0 small-weight conversion (merged)
    rmsnorm_cvt_kernel<<<dim3(M_ + CVB), blk, 0, stream>>>(
        h, norm_w, xn_bf,
        xp_w, xpw_b[0], N_XP,
        dtp_w, dtpw_b[0], N_DTP);

    for (int l = 0; l < L_; ++l) {
        const int s = l & 1;
        // in_proj (MFMA, fp32 weights direct): x -> xb bf16, z -> silu -> szb
        gemm_mfma_kernel<7, 64, true><<<dim3(2 * DI_ / 64, M_ / 128, 1), blk, 0, stream>>>(
            xn_bf, ip_w + (size_t)l * 2 * DI_ * D_,
            (float*)xb_bf, (float*)szb_bf, M_, 2 * DI_, D_, D_);
        // conv + silu: xi_bf [m][e] (sole xi copy; scan reads it too)
        conv_silu_kernel<<<dim3(M_ / 64, DI_ / 64), blk, 0, stream>>>(
            xb_bf, conv_w + (size_t)l * DI_ * DC_, conv_b + (size_t)l * DI_,
            xi_bf);
        // x_proj (split-K MFMA) + reduce -> dtr_bf, Bc, Cc
        xproj_mfma_kernel<<<dim3(XKS, M_ / 128), blk, 0, stream>>>(
            xi_bf, xpw_b[s], Pbuf);
        xproj_reduce_kernel<<<dim3((M_ * 96 + 255) / 256), blk, 0, stream>>>(
            Pbuf, Bc, Cc, dtr_bf);
        // chunked scan, channel-per-thread, dt_proj fused (512 blocks)
        scan_chunk1_kernel<<<dim3(NC * B_ * DI_ / 256), blk, 0, stream>>>(
            dtr_bf, dtpw_b[s], dtp_b + (size_t)l * DI_, Bc, xi_bf,
            A_log + (size_t)l * DI_ * DS_, Ap, Hp);
        scan_chunk2_kernel<<<dim3(B_ * DI_ * DS_ / 256), blk, 0, stream>>>(Ap, Hp);
        scan_chunk3_kernel<<<dim3(NC * B_ * DI_ / 256), blk, 0, stream>>>(
            dtr_bf, dtpw_b[s], dtp_b + (size_t)l * DI_, Bc, Cc, xi_bf, szb_bf,
            A_log + (size_t)l * DI_ * DS_, D_param + (size_t)l * DI_, Hp, yb_bf);
        // out_proj (fp32 weights direct, split-K=OPK; BF16 partials into xz)
        gemm_mfma_kernel<8, 64, true><<<dim3(D_ / 64, M_ / 128, OPK), blk, 0, stream>>>(
            yb_bf, op_w + (size_t)l * D_ * DI_,
            (float*)Pop, nullptr, M_, D_, DI_, DI_ / OPK);
        // reduce + residual + next rmsnorm + next layer's small cvt (merged)
        const int docvt = (l + 1 < L_);
        outproj_rmsnorm_cvt_kernel<<<dim3(M_ + (docvt ? CVB : 0)), blk, 0, stream>>>(
            Pop, h, norm_w + (size_t)((l + 1) & 3) * D_, xn_bf, l < L_ - 1,
            xp_w + (size_t)(l + 1) * 96 * DI_, xpw_b[s ^ 1], docvt ? N_XP : 0,
            dtp_w + (size_t)(l + 1) * DI_ * DR_, dtpw_b[s ^ 1], docvt ? N_DTP : 0);
    }

    final_rmsnorm_kernel<<<dim3(B_ * S_), blk, 0, stream>>>(h, fnw, out);
}

// Round 10
// 660.863 us; speedup vs baseline: 1.0743x; 1.0743x over previous
//
#include <hip/hip_runtime.h>
#include <math.h>

#define B_ 2
#define S_ 512
#define P_ 64
#define T_ 576          // P_+S_
#define D_ 1024
#define L_ 4
#define DI_ 2048
#define DS_ 16
#define DC_ 4
#define DR_ 64
#define PCD_ 768
#define M_ (B_*T_)      // 1152
#define CCH 18          // scan chunk length (T_/CCH = 32 chunks)
#define NC (T_/CCH)     // 32 chunks -> NC*B*DI threads = 512 blocks
#define XKS 16          // x_proj K-splits (KC = 2048/16 = 128)
#define OPK 4           // out_proj K-splits

// per-layer weight-conversion sizes (float4 units) and block count
#define N_IP (2*DI_*D_/4)
#define N_XP (96*DI_/4)
#define N_DTP (DI_*DR_/4)
#define N_OP (D_*DI_/4)
#define CVB ((N_IP + N_XP + N_DTP + N_OP + 255) / 256)
// weight set size in shorts
#define SETSZ ((size_t)2*DI_*D_ + 96*DI_ + DI_*DR_ + D_*DI_)

typedef __attribute__((ext_vector_type(8))) short bf16x8;
typedef __attribute__((ext_vector_type(4))) float f32x4;

__device__ __forceinline__ float silu_f(float v) { return v / (1.f + __expf(-v)); }
__device__ __forceinline__ float softplus_f(float v) {
    return fmaxf(v, 0.f) + log1pf(__expf(-fabsf(v)));
}
__device__ __forceinline__ unsigned short bf16_rne(float x) {
    unsigned int b = __float_as_uint(x);
    b += 0x7fffu + ((b >> 16) & 1u);
    return (unsigned short)(b >> 16);
}
__device__ __forceinline__ float bf16_to_f(unsigned short u) {
    return __uint_as_float((unsigned int)u << 16);
}

typedef const void __attribute__((address_space(1)))* gas_t;
typedef void __attribute__((address_space(3)))* las_t;
__device__ __forceinline__ void async16(const void* g, void* l) {
    __builtin_amdgcn_global_load_lds((gas_t)g, (las_t)l, 16, 0, 0);
}

// shared cvt4 tail: converts one 256-thread block's worth of fp32->bf16
__device__ __forceinline__ void cvt4_body(int i,
    const float* s0, unsigned short* d0, int n0,
    const float* s1, unsigned short* d1, int n1,
    const float* s2, unsigned short* d2, int n2,
    const float* s3, unsigned short* d3, int n3)
{
    const float* s; unsigned short* d; int off;
    if (i < n0)                     { s = s0; d = d0; off = i; }
    else if (i < n0 + n1)           { s = s1; d = d1; off = i - n0; }
    else if (i < n0 + n1 + n2)      { s = s2; d = d2; off = i - n0 - n1; }
    else if (i < n0 + n1 + n2 + n3) { s = s3; d = d3; off = i - n0 - n1 - n2; }
    else return;
    const float4 v = ((const float4*)s)[off];
    ushort4 o;
    o.x = bf16_rne(v.x); o.y = bf16_rne(v.y);
    o.z = bf16_rne(v.z); o.w = bf16_rne(v.w);
    ((ushort4*)d)[off] = o;
}

// ---------------------------------------------------------------------------
// bf16 MFMA GEMM: C[m,n] (+)= sum_k A[m,k]*W[n,k]. Tile = 128 x BN.
// 2-phase pipeline: LDS double-buffered; tile t+1's global_load_lds issued
// BEFORE tile t's ds_read+MFMA, one barrier per K-step (R8 structure, 667us).
// NOTE: R9's fp32-weight-direct variant REGRESSED (+43us): fp32 B doubles
// fetch bytes and the reg-staged ds_write_b128 is an 8-way bank conflict.
// bf16 weight sets + merged cvt (below) is the proven configuration.
// EPI: 6 = split-K fp32 partial store (prepend GEMMs);
//      7 = in_proj fused epilogue, bf16 outs: n<DI -> xb; n>=DI -> silu->szb;
//      8 = split-K BF16 partial store (out_proj; reduce tolerates bf16).
// ---------------------------------------------------------------------------
template<int EPI, int BN>
__global__ __launch_bounds__(256) void gemm_mfma_kernel(
    const unsigned short* __restrict__ A, const unsigned short* __restrict__ W,
    float* __restrict__ C, float* __restrict__ C2,
    int M, int N, int K, int Kchunk)
{
    constexpr int NF = BN / 32;              // n-frags per wave (2 or 4)
    __shared__ unsigned short As[2][128 * 32];
    __shared__ unsigned short Bs[2][BN * 32];
    const int tid = threadIdx.x;
    const int wave = tid >> 6;
    const int lane = tid & 63;
    const int m0 = blockIdx.y * 128, n0 = blockIdx.x * BN;
    const int kbase = blockIdx.z * Kchunk;
    const int wm = (wave >> 1) * 64, wn = (wave & 1) * (BN / 2);

    const int srow = (wave << 5) + (lane >> 2);
    const int selem = (lane & 3) * 8;
    const unsigned short* gA = A + (size_t)(m0 + srow) * K + kbase + selem;
    const unsigned short* gB = W + (size_t)(n0 + srow) * K + kbase + selem;
    const int lofs = (wave << 5) * 32;

    f32x4 acc[4][NF];
    #pragma unroll
    for (int i = 0; i < 4; ++i)
        #pragma unroll
        for (int j = 0; j < NF; ++j)
            acc[i][j] = (f32x4){0.f, 0.f, 0.f, 0.f};

    const int fr = lane & 15;
    const int fq = lane >> 4;
    const int aoff = (wm + fr) * 32 + fq * 8;
    const int boff = (wn + fr) * 32 + fq * 8;

    const int NT = Kchunk >> 5;              // 32-wide K steps

    #define STAGE(b, t) do {                                              \
        const unsigned short* pA = gA + (t) * 32;                         \
        async16(pA, &As[b][lofs]);                                        \
        async16(pA + (size_t)16 * K, &As[b][lofs + 16 * 32]);             \
        if (BN == 128 || wave < BN / 32) {                                \
            const unsigned short* pB = gB + (t) * 32;                     \
            async16(pB, &Bs[b][lofs]);                                    \
            async16(pB + (size_t)16 * K, &Bs[b][lofs + 16 * 32]);         \
        }                                                                 \
    } while (0)

    STAGE(0, 0);
    __syncthreads();                         // buf0 ready
    for (int t = 0; t < NT; ++t) {
        const int cur = t & 1;
        if (t + 1 < NT) STAGE(cur ^ 1, t + 1);   // prefetch under compute
        bf16x8 af[4], bf[NF];
        #pragma unroll
        for (int i = 0; i < 4; ++i) af[i] = *(const bf16x8*)&As[cur][aoff + i * 512];
        #pragma unroll
        for (int j = 0; j < NF; ++j) bf[j] = *(const bf16x8*)&Bs[cur][boff + j * 512];
        #pragma unroll
        for (int i = 0; i < 4; ++i)
            #pragma unroll
            for (int j = 0; j < NF; ++j)
                acc[i][j] = __builtin_amdgcn_mfma_f32_16x16x32_bf16(
                    af[i], bf[j], acc[i][j], 0, 0, 0);
        __syncthreads();
    }
    #undef STAGE

    // C/D layout (m89-verified): col = lane&15, row = (lane>>4)*4 + reg
    #pragma unroll
    for (int i = 0; i < 4; ++i) {
        const int m = m0 + wm + i * 16 + fq * 4;
        #pragma unroll
        for (int j = 0; j < NF; ++j) {
            const int n = n0 + wn + j * 16 + fr;
            if (EPI == 6) {
                float* p = C + ((size_t)blockIdx.z * M + m) * N + n;
                #pragma unroll
                for (int r = 0; r < 4; ++r)
                    p[(size_t)r * N] = acc[i][j][r];
            } else if (EPI == 8) {
                unsigned short* p = (unsigned short*)C +
                                    ((size_t)blockIdx.z * M + m) * N + n;
                #pragma unroll
                for (int r = 0; r < 4; ++r)
                    p[(size_t)r * N] = bf16_rne(acc[i][j][r]);
            } else if (EPI == 7) {
                if (n < DI_) {
                    unsigned short* p = (unsigned short*)C + (size_t)m * DI_ + n;
                    #pragma unroll
                    for (int r = 0; r < 4; ++r)
                        p[(size_t)r * DI_] = bf16_rne(acc[i][j][r]);
                } else {
                    unsigned short* p = (unsigned short*)C2 + (size_t)m * DI_ + (n - DI_);
                    #pragma unroll
                    for (int r = 0; r < 4; ++r)
                        p[(size_t)r * DI_] = bf16_rne(silu_f(acc[i][j][r]));
                }
            }
        }
    }
}

// ---------------------------------------------------------------------------
// x_proj split-K MFMA (2-phase pipelined):
// P[ks][m][96] = xi_bf[m, ks*128:(ks+1)*128] @ W[96, ...]^T
// ---------------------------------------------------------------------------
__global__ __launch_bounds__(256) void xproj_mfma_kernel(
    const unsigned short* __restrict__ A,   // [M, 2048] bf16
    const unsigned short* __restrict__ W,   // [96, 2048] bf16
    float* __restrict__ P)                  // [XKS, M, 96]
{
    __shared__ unsigned short As[2][128 * 32];
    __shared__ unsigned short Bs[2][96 * 32];
    const int tid = threadIdx.x;
    const int wave = tid >> 6;
    const int lane = tid & 63;
    const int m0 = blockIdx.y * 128;
    const int kbase = blockIdx.x * (DI_ / XKS);   // 128
    const int wm = (wave >> 1) * 64, wn = (wave & 1) * 48;

    const int srow = (wave << 5) + (lane >> 2);
    const int selem = (lane & 3) * 8;
    const unsigned short* gA = A + (size_t)(m0 + srow) * DI_ + kbase + selem;
    const unsigned short* gB = W + (size_t)srow * DI_ + kbase + selem;
    const int lofs = (wave << 5) * 32;

    f32x4 acc[4][3];
    #pragma unroll
    for (int i = 0; i < 4; ++i)
        #pragma unroll
        for (int j = 0; j < 3; ++j)
            acc[i][j] = (f32x4){0.f, 0.f, 0.f, 0.f};

    const int fr = lane & 15;
    const int fq = lane >> 4;
    const int aoff = (wm + fr) * 32 + fq * 8;
    const int boff = (wn + fr) * 32 + fq * 8;

    #define XSTAGE(b, t) do {                                             \
        const unsigned short* pA = gA + (t) * 32;                         \
        async16(pA, &As[b][lofs]);                                        \
        async16(pA + (size_t)16 * DI_, &As[b][lofs + 16 * 32]);           \
        if (wave < 3) {                                                   \
            const unsigned short* pB = gB + (t) * 32;                     \
            async16(pB, &Bs[b][lofs]);                                    \
            async16(pB + (size_t)16 * DI_, &Bs[b][lofs + 16 * 32]);       \
        }                                                                 \
    } while (0)

    XSTAGE(0, 0);
    __syncthreads();
    #pragma unroll
    for (int t = 0; t < 4; ++t) {
        const int cur = t & 1;
        if (t + 1 < 4) XSTAGE(cur ^ 1, t + 1);
        bf16x8 af[4], bf[3];
        #pragma unroll
        for (int i = 0; i < 4; ++i) af[i] = *(const bf16x8*)&As[cur][aoff + i * 512];
        #pragma unroll
        for (int j = 0; j < 3; ++j) bf[j] = *(const bf16x8*)&Bs[cur][boff + j * 512];
        #pragma unroll
        for (int i = 0; i < 4; ++i)
            #pragma unroll
            for (int j = 0; j < 3; ++j)
                acc[i][j] = __builtin_amdgcn_mfma_f32_16x16x32_bf16(
                    af[i], bf[j], acc[i][j], 0, 0, 0);
        __syncthreads();
    }
    #undef XSTAGE

    float* Pb = P + ((size_t)blockIdx.x * M_ + m0) * 96;
    #pragma unroll
    for (int i = 0; i < 4; ++i) {
        const int m = wm + i * 16 + fq * 4;
        #pragma unroll
        for (int j = 0; j < 3; ++j) {
            const int n = wn + j * 16 + fr;
            #pragma unroll
            for (int r = 0; r < 4; ++r)
                Pb[(size_t)(m + r) * 96 + n] = acc[i][j][r];
        }
    }
}

// reduce partials; emit dtr_bf [m][64] plus per-row scan streams
// Bc[m][16], Cc[m][16] (contiguous states per timestep).
__global__ __launch_bounds__(256) void xproj_reduce_kernel(
    const float* __restrict__ P, float* __restrict__ Bc, float* __restrict__ Cc,
    unsigned short* __restrict__ dtr_bf)
{
    const int i = blockIdx.x * 256 + threadIdx.x;
    if (i >= M_ * 96) return;
    float s = 0.f;
    #pragma unroll
    for (int ks = 0; ks < XKS; ++ks) s += P[(size_t)ks * (M_ * 96) + i];
    const int m = i / 96;
    const int n = i - m * 96;
    if (n < DR_)            dtr_bf[(size_t)m * DR_ + n] = bf16_rne(s);
    else if (n < DR_ + DS_) Bc[(size_t)m * DS_ + (n - DR_)] = s;
    else                    Cc[(size_t)m * DS_ + (n - DR_ - DS_)] = s;
}

// ---------------------------------------------------------------------------
// Merged prepend-phase conversions: pc fp32->bf16 (blocks 0..95), w1
// transpose (96..287), w2 transpose (288..543). Block-uniform branches.
// (R9's one orthogonal win — replaces 3 serial launches.)
// ---------------------------------------------------------------------------
__global__ __launch_bounds__(256) void prep_cvt_kernel(
    const float* __restrict__ pc, unsigned short* __restrict__ pcb,
    const float* __restrict__ w1, unsigned short* __restrict__ w1t,
    const float* __restrict__ w2, unsigned short* __restrict__ w2t)
{
    __shared__ float t[64][65];
    const int bid = blockIdx.x;
    const int tx = threadIdx.x & 63;
    const int ty = threadIdx.x >> 6;
    if (bid < 96) {
        const int i = bid * 256 + threadIdx.x;
        const float4 v = ((const float4*)pc)[i];
        ushort4 o;
        o.x = bf16_rne(v.x); o.y = bf16_rne(v.y);
        o.z = bf16_rne(v.z); o.w = bf16_rne(v.w);
        ((ushort4*)pcb)[i] = o;
        return;
    }
    const float* in; unsigned short* outp; int K, N, k0, n0;
    if (bid < 96 + 192) {
        const int b = bid - 96;
        K = PCD_; N = D_; in = w1; outp = w1t;
        k0 = (b % (PCD_ / 64)) * 64; n0 = (b / (PCD_ / 64)) * 64;
    } else {
        const int b = bid - 288;
        K = D_; N = D_; in = w2; outp = w2t;
        k0 = (b % (D_ / 64)) * 64; n0 = (b / (D_ / 64)) * 64;
    }
    #pragma unroll
    for (int j = 0; j < 16; ++j) {
        const int kk = ty * 16 + j;
        t[kk][tx] = in[(size_t)(k0 + kk) * N + n0 + tx];
    }
    __syncthreads();
    #pragma unroll
    for (int j = 0; j < 16; ++j) {
        const int nn = ty * 16 + j;
        outp[(size_t)(n0 + nn) * K + k0 + tx] = bf16_rne(t[tx][nn]);
    }
}

// generalized split-K reduces (stride MN between partials)
__global__ __launch_bounds__(256) void reduce_silu_bf16_kernel(
    const float* __restrict__ P, unsigned short* __restrict__ o, int MN, int ns)
{
    const int i = blockIdx.x * 256 + threadIdx.x;
    if (i >= MN) return;
    float s = 0.f;
    for (int k = 0; k < ns; ++k) s += P[(size_t)k * MN + i];
    o[i] = bf16_rne(silu_f(s));
}
__global__ __launch_bounds__(256) void reduce_fp32_kernel(
    const float* __restrict__ P, float* __restrict__ o, int MN, int ns)
{
    const int i = blockIdx.x * 256 + threadIdx.x;
    if (i >= MN) return;
    float s = 0.f;
    for (int k = 0; k < ns; ++k) s += P[(size_t)k * MN + i];
    o[i] = s;
}

// out_proj split-K reduce (BF16 partials) + residual add into h + (optional)
// next layer's rmsnorm->bf16, PLUS (blocks >= M_) next layer's weight cvt.
__global__ __launch_bounds__(256) void outproj_rmsnorm_cvt_kernel(
    const unsigned short* __restrict__ P, float* __restrict__ h,
    const float* __restrict__ w, unsigned short* __restrict__ outb, int donorm,
    const float* s0, unsigned short* d0, int n0,
    const float* s1, unsigned short* d1, int n1,
    const float* s2, unsigned short* d2, int n2,
    const float* s3, unsigned short* d3, int n3)
{
    const int bid = blockIdx.x;
    if (bid >= M_) {
        cvt4_body((bid - M_) * 256 + threadIdx.x,
                  s0, d0, n0, s1, d1, n1, s2, d2, n2, s3, d3, n3);
        return;
    }
    const int r = bid;
    const int i = r * 256 + threadIdx.x;        // float4/ushort4 col index
    float4 v = ((float4*)h)[i];
    #pragma unroll
    for (int k = 0; k < OPK; ++k) {
        const ushort4 a4 = ((const ushort4*)P)[(size_t)k * (M_ * D_ / 4) + i];
        v.x += bf16_to_f(a4.x); v.y += bf16_to_f(a4.y);
        v.z += bf16_to_f(a4.z); v.w += bf16_to_f(a4.w);
    }
    ((float4*)h)[i] = v;
    if (!donorm) return;
    float ss = v.x * v.x + v.y * v.y + v.z * v.z + v.w * v.w;
    ss += __shfl_xor(ss, 32, 64);
    ss += __shfl_xor(ss, 16, 64);
    ss += __shfl_xor(ss, 8, 64);
    ss += __shfl_xor(ss, 4, 64);
    ss += __shfl_xor(ss, 2, 64);
    ss += __shfl_xor(ss, 1, 64);
    __shared__ float red[4];
    if ((threadIdx.x & 63) == 0) red[threadIdx.x >> 6] = ss;
    __syncthreads();
    const float tot = red[0] + red[1] + red[2] + red[3];
    const float scale = rsqrtf(tot * (1.f / D_) + 1e-5f);
    const float4 wv = ((const float4*)w)[threadIdx.x];
    ushort4 o;
    o.x = bf16_rne(v.x * scale * wv.x);
    o.y = bf16_rne(v.y * scale * wv.y);
    o.z = bf16_rne(v.z * scale * wv.z);
    o.w = bf16_rne(v.w * scale * wv.w);
    ((ushort4*)(outb + (size_t)r * D_))[threadIdx.x] = o;
}

// h[b*T+t, :] = (t < P) ? p[b*P+t, :] : x[b*S + (t-P), :]
__global__ __launch_bounds__(256) void assemble_h_kernel(
    const float* __restrict__ p, const float* __restrict__ x, float* __restrict__ h)
{
    const int idx = blockIdx.x * 256 + threadIdx.x;
    const int r = idx >> 8;
    const int c = idx & 255;
    const int b = r / T_;
    const int t = r - b * T_;
    float4 v;
    if (t < P_) v = ((const float4*)p)[(size_t)(b * P_ + t) * 256 + c];
    else        v = ((const float4*)x)[(size_t)(b * S_ + (t - P_)) * 256 + c];
    ((float4*)h)[idx] = v;
}

// rmsnorm -> bf16 (feeds in_proj MFMA) + (blocks >= M_) layer-0 weight cvt.
__global__ __launch_bounds__(256) void rmsnorm_cvt_kernel(
    const float* __restrict__ x, const float* __restrict__ w,
    unsigned short* __restrict__ outb,
    const float* s0, unsigned short* d0, int n0,
    const float* s1, unsigned short* d1, int n1,
    const float* s2, unsigned short* d2, int n2,
    const float* s3, unsigned short* d3, int n3)
{
    const int bid = blockIdx.x;
    if (bid >= M_) {
        cvt4_body((bid - M_) * 256 + threadIdx.x,
                  s0, d0, n0, s1, d1, n1, s2, d2, n2, s3, d3, n3);
        return;
    }
    const int r = bid;
    const float4 v = ((const float4*)(x + (size_t)r * D_))[threadIdx.x];
    float ss = v.x * v.x + v.y * v.y + v.z * v.z + v.w * v.w;
    ss += __shfl_xor(ss, 32, 64);
    ss += __shfl_xor(ss, 16, 64);
    ss += __shfl_xor(ss, 8, 64);
    ss += __shfl_xor(ss, 4, 64);
    ss += __shfl_xor(ss, 2, 64);
    ss += __shfl_xor(ss, 1, 64);
    __shared__ float red[4];
    if ((threadIdx.x & 63) == 0) red[threadIdx.x >> 6] = ss;
    __syncthreads();
    const float tot = red[0] + red[1] + red[2] + red[3];
    const float scale = rsqrtf(tot * (1.f / D_) + 1e-5f);
    const float4 wv = ((const float4*)w)[threadIdx.x];
    ushort4 o;
    o.x = bf16_rne(v.x * scale * wv.x);
    o.y = bf16_rne(v.y * scale * wv.y);
    o.z = bf16_rne(v.z * scale * wv.z);
    o.w = bf16_rne(v.w * scale * wv.w);
    ((ushort4*)(outb + (size_t)r * D_))[threadIdx.x] = o;
}

// final rmsnorm (fp32 out): rows over B*S; reads h[b*T+P+s]
__global__ __launch_bounds__(256) void final_rmsnorm_kernel(
    const float* __restrict__ h, const float* __restrict__ w, float* __restrict__ out)
{
    const int r = blockIdx.x;
    const int b = r / S_;
    const int s = r - b * S_;
    const int hr = b * T_ + P_ + s;
    const float4 v = ((const float4*)(h + (size_t)hr * D_))[threadIdx.x];
    float ss = v.x * v.x + v.y * v.y + v.z * v.z + v.w * v.w;
    ss += __shfl_xor(ss, 32, 64);
    ss += __shfl_xor(ss, 16, 64);
    ss += __shfl_xor(ss, 8, 64);
    ss += __shfl_xor(ss, 4, 64);
    ss += __shfl_xor(ss, 2, 64);
    ss += __shfl_xor(ss, 1, 64);
    __shared__ float red[4];
    if ((threadIdx.x & 63) == 0) red[threadIdx.x >> 6] = ss;
    __syncthreads();
    const float tot = red[0] + red[1] + red[2] + red[3];
    const float scale = rsqrtf(tot * (1.f / D_) + 1e-5f);
    const float4 wv = ((const float4*)w)[threadIdx.x];
    float4 o;
    o.x = v.x * scale * wv.x; o.y = v.y * scale * wv.y;
    o.z = v.z * scale * wv.z; o.w = v.w * scale * wv.w;
    ((float4*)(out + (size_t)r * D_))[threadIdx.x] = o;
}

// ---------------------------------------------------------------------------
// Fused causal depthwise conv (DC=4) + bias + silu. Reads compact bf16 xb,
// emits xi as bf16 [m][e] (sole copy).
// ---------------------------------------------------------------------------
__global__ __launch_bounds__(256) void conv_silu_kernel(
    const unsigned short* __restrict__ xb, const float* __restrict__ cw,
    const float* __restrict__ cb, unsigned short* __restrict__ xib)
{
    __shared__ float xs[67][64];    // rows r0-3 .. r0+63
    const int tid = threadIdx.x;
    const int tx = tid & 63;
    const int ty = tid >> 6;        // 0..3
    const int r0 = blockIdx.x * 64;
    const int e0 = blockIdx.y * 64;
    const int bt0 = (r0 / T_) * T_; // batch start row

    for (int j = ty; j < 67; j += 4) {
        const int r = r0 + j - 3;
        xs[j][tx] = (r >= bt0) ? bf16_to_f(xb[(size_t)r * DI_ + e0 + tx]) : 0.f;
    }
    __syncthreads();
    const float4 w = *(const float4*)(cw + (size_t)(e0 + tx) * 4);
    const float bias = cb[e0 + tx];
    #pragma unroll
    for (int j = 0; j < 16; ++j) {
        const int rl = ty * 16 + j;
        float v = bias;
        v = fmaf(w.x, xs[rl + 0][tx], v);   // x[r-3]
        v = fmaf(w.y, xs[rl + 1][tx], v);   // x[r-2]
        v = fmaf(w.z, xs[rl + 2][tx], v);   // x[r-1]
        v = fmaf(w.w, xs[rl + 3][tx], v);   // x[r]
        xib[(size_t)(r0 + rl) * DI_ + e0 + tx] = bf16_rne(silu_f(v));
    }
}

// ---------------------------------------------------------------------------
// Chunked selective scan with FUSED dt_proj (3 plain-stream kernels; kernel
// boundaries provide cross-XCD coherence — the cooperative fusion raced).
// dt recomputed in scan1 and scan3 with identical op order.
// ---------------------------------------------------------------------------
__global__ __launch_bounds__(256) void scan_chunk1_kernel(
    const unsigned short* __restrict__ dtr,   // [M, 64] bf16
    const unsigned short* __restrict__ dtw,   // [DI, 64] bf16
    const float* __restrict__ dtbias,         // [DI]
    const float* __restrict__ Bc,             // [M, DS]
    const unsigned short* __restrict__ xib,   // [M, DI] bf16
    const float* __restrict__ A_log,
    float* __restrict__ Ap, float* __restrict__ Hp)
{
    __shared__ float4 Bs[CCH][4];
    __shared__ float dtrs[CCH][DR_];          // 4.6KB, broadcast reads
    const int tid = threadIdx.x;
    const int e = ((blockIdx.x & 7) << 8) + tid;   // DI/256 = 8 blocks per (c,b)
    const int cb = blockIdx.x >> 3;                // c*B + b
    const int b = cb & (B_ - 1);
    const int c = cb >> 1;
    const int r0 = b * T_ + c * CCH;
    for (int i = tid; i < CCH * DS_; i += 256)
        ((float*)Bs)[i] = Bc[(size_t)r0 * DS_ + i];
    for (int i = tid; i < CCH * DR_ / 4; i += 256) {
        const ushort4 v4 = ((const ushort4*)(dtr + (size_t)r0 * DR_))[i];
        float* d = &dtrs[0][0] + i * 4;
        d[0] = bf16_to_f(v4.x); d[1] = bf16_to_f(v4.y);
        d[2] = bf16_to_f(v4.z); d[3] = bf16_to_f(v4.w);
    }
    float A2[DS_], h[DS_], a[DS_];
    const float* Ae = A_log + (size_t)e * DS_;
    #pragma unroll
    for (int s = 0; s < DS_; ++s) {
        A2[s] = -__expf(Ae[s]) * 1.44269504f;   // pre-scale for exp2
        h[s] = 0.f; a[s] = 1.f;
    }
    __syncthreads();
    // fused dt_proj for this thread's channel e
    float dt[CCH];
    {
        float w[DR_];
        const ushort4* wp = (const ushort4*)(dtw + (size_t)e * DR_);
        #pragma unroll
        for (int q = 0; q < 16; ++q) {
            const ushort4 v = wp[q];
            w[q * 4 + 0] = bf16_to_f(v.x);
            w[q * 4 + 1] = bf16_to_f(v.y);
            w[q * 4 + 2] = bf16_to_f(v.z);
            w[q * 4 + 3] = bf16_to_f(v.w);
        }
        const float bb = dtbias[e];
        #pragma unroll
        for (int t = 0; t < CCH; ++t) {
            float acc = 0.f;
            #pragma unroll
            for (int r = 0; r < DR_; ++r) acc = fmaf(dtrs[t][r], w[r], acc);
            dt[t] = softplus_f(acc + bb);
        }
    }
    const unsigned short* up = xib + (size_t)r0 * DI_ + e;
    #pragma unroll
    for (int t = 0; t < CCH; ++t) {
        const float dtv = dt[t];
        const float dtu = dtv * bf16_to_f(up[(size_t)t * DI_]);
        #pragma unroll
        for (int q = 0; q < 4; ++q) {
            const float4 bq = Bs[t][q];
            const float* bb = &bq.x;
            #pragma unroll
            for (int j = 0; j < 4; ++j) {
                const int s = q * 4 + j;
                const float da = __builtin_amdgcn_exp2f(dtv * A2[s]);
                a[s] *= da;
                h[s] = fmaf(da, h[s], bb[j] * dtu);
            }
        }
    }
    // layout [c][b][s][e]: every store coalesced across lanes
    const size_t o = (size_t)cb * DS_ * DI_ + e;
    #pragma unroll
    for (int s = 0; s < DS_; ++s) {
        Ap[o + (size_t)s * DI_] = a[s];
        Hp[o + (size_t)s * DI_] = h[s];
    }
}

__global__ __launch_bounds__(256) void scan_chunk2_kernel(
    float* __restrict__ Ap, float* __restrict__ Hp)
{
    const int g = blockIdx.x * 256 + threadIdx.x;
    float h = 0.f;
    #pragma unroll
    for (int c = 0; c < NC; ++c) {
        const size_t o = (size_t)c * (B_ * DI_ * DS_) + g;
        const float ap = Ap[o];
        const float hp = Hp[o];
        Hp[o] = h;
        h = fmaf(ap, h, hp);
    }
}

__global__ __launch_bounds__(256) void scan_chunk3_kernel(
    const unsigned short* __restrict__ dtr,   // [M, 64] bf16
    const unsigned short* __restrict__ dtw,   // [DI, 64] bf16
    const float* __restrict__ dtbias,         // [DI]
    const float* __restrict__ Bc,             // [M, DS]
    const float* __restrict__ Cc,             // [M, DS]
    const unsigned short* __restrict__ xib,   // [M, DI] bf16
    const unsigned short* __restrict__ szb,   // [M, DI] bf16 silu(z)
    const float* __restrict__ A_log, const float* __restrict__ Dp,
    const float* __restrict__ Hin, unsigned short* __restrict__ y)
{
    __shared__ float4 Bs[CCH][4], Cs[CCH][4];
    __shared__ float dtrs[CCH][DR_];
    const int tid = threadIdx.x;
    const int e = ((blockIdx.x & 7) << 8) + tid;
    const int cb = blockIdx.x >> 3;
    const int b = cb & (B_ - 1);
    const int c = cb >> 1;
    const int r0 = b * T_ + c * CCH;
    for (int i = tid; i < CCH * DS_; i += 256) {
        ((float*)Bs)[i] = Bc[(size_t)r0 * DS_ + i];
        ((float*)Cs)[i] = Cc[(size_t)r0 * DS_ + i];
    }
    for (int i = tid; i < CCH * DR_ / 4; i += 256) {
        const ushort4 v4 = ((const ushort4*)(dtr + (size_t)r0 * DR_))[i];
        float* d = &dtrs[0][0] + i * 4;
        d[0] = bf16_to_f(v4.x); d[1] = bf16_to_f(v4.y);
        d[2] = bf16_to_f(v4.z); d[3] = bf16_to_f(v4.w);
    }
    float A2[DS_], h[DS_];
    const float* Ae = A_log + (size_t)e * DS_;
    const float dpe = Dp[e];
    const size_t ho = (size_t)cb * DS_ * DI_ + e;
    #pragma unroll
    for (int s = 0; s < DS_; ++s) {
        A2[s] = -__expf(Ae[s]) * 1.44269504f;
        h[s] = Hin[ho + (size_t)s * DI_];
    }
    __syncthreads();
    // fused dt_proj (identical op order to scan1 -> identical dt values)
    float dt[CCH];
    {
        float w[DR_];
        const ushort4* wp = (const ushort4*)(dtw + (size_t)e * DR_);
        #pragma unroll
        for (int q = 0; q < 16; ++q) {
            const ushort4 v = wp[q];
            w[q * 4 + 0] = bf16_to_f(v.x);
            w[q * 4 + 1] = bf16_to_f(v.y);
            w[q * 4 + 2] = bf16_to_f(v.z);
            w[q * 4 + 3] = bf16_to_f(v.w);
        }
        const float bb = dtbias[e];
        #pragma unroll
        for (int t = 0; t < CCH; ++t) {
            float acc = 0.f;
            #pragma unroll
            for (int r = 0; r < DR_; ++r) acc = fmaf(dtrs[t][r], w[r], acc);
            dt[t] = softplus_f(acc + bb);
        }
    }
    const unsigned short* up = xib + (size_t)r0 * DI_ + e;
    const unsigned short* sp = szb + (size_t)r0 * DI_ + e;
    unsigned short* yp = y + (size_t)r0 * DI_ + e;
    #pragma unroll
    for (int t = 0; t < CCH; ++t) {
        const float dtv = dt[t];
        const float u   = bf16_to_f(up[(size_t)t * DI_]);
        const float dtu = dtv * u;
        float y0 = 0.f, y1 = 0.f, y2 = 0.f, y3 = 0.f;
        #pragma unroll
        for (int q = 0; q < 4; ++q) {
            const float4 bq = Bs[t][q];
            const float4 cq = Cs[t][q];
            const float* bb = &bq.x;
            const float* cc = &cq.x;
            #pragma unroll
            for (int j = 0; j < 4; ++j) {
                const int s = q * 4 + j;
                const float da = __builtin_amdgcn_exp2f(dtv * A2[s]);
                h[s] = fmaf(da, h[s], bb[j] * dtu);
                if (j == 0)      y0 = fmaf(h[s], cc[j], y0);
                else if (j == 1) y1 = fmaf(h[s], cc[j], y1);
                else if (j == 2) y2 = fmaf(h[s], cc[j], y2);
                else             y3 = fmaf(h[s], cc[j], y3);
            }
        }
        const float ysum = (y0 + y1) + (y2 + y3);
        const float yv = fmaf(u, dpe, ysum) * bf16_to_f(sp[(size_t)t * DI_]);
        yp[(size_t)t * DI_] = bf16_rne(yv);
    }
}

extern "C" void kernel_launch(void* const* d_in, const int* in_sizes, int n_in,
                              void* d_out, int out_size, void* d_ws, size_t ws_size,
                              hipStream_t stream)
{
    const float* x       = (const float*)d_in[0];
    const float* pc      = (const float*)d_in[1];
    const float* pre_w1  = (const float*)d_in[2];
    const float* pre_w2  = (const float*)d_in[3];
    const float* norm_w  = (const float*)d_in[4];
    const float* ip_w    = (const float*)d_in[5];
    const float* conv_w  = (const float*)d_in[6];
    const float* conv_b  = (const float*)d_in[7];
    const float* xp_w    = (const float*)d_in[8];
    const float* dtp_w   = (const float*)d_in[9];
    const float* dtp_b   = (const float*)d_in[10];
    const float* A_log   = (const float*)d_in[11];
    const float* D_param = (const float*)d_in[12];
    const float* op_w    = (const float*)d_in[13];
    const float* fnw     = (const float*)d_in[14];
    float* out = (float*)d_out;

    float* ws = (float*)d_ws;
    float* h    = ws;  ws += (size_t)M_ * D_;            // fp32 residual
    float* xz   = ws;  ws += (size_t)M_ * 2 * DI_;       // scan partials / Pop
    float* scr  = ws;  ws += (size_t)M_ * DI_;           // prepend GEMM2 partials
    float* Pbuf = ws;  ws += (size_t)XKS * M_ * 96;      // x_proj / prepend partials
    float* Bc   = ws;  ws += (size_t)DS_ * M_;           // B stream [m][s]
    float* Cc   = ws;  ws += (size_t)DS_ * M_;           // C stream [m][s]
    unsigned short* xn_bf  = (unsigned short*)ws;  ws += (size_t)M_ * D_ / 2;
    unsigned short* yb_bf  = (unsigned short*)ws;  ws += (size_t)M_ * DI_ / 2;
    unsigned short* xi_bf  = (unsigned short*)ws;  ws += (size_t)M_ * DI_ / 2;
    unsigned short* xb_bf  = (unsigned short*)ws;  ws += (size_t)M_ * DI_ / 2;
    unsigned short* szb_bf = (unsigned short*)ws;  ws += (size_t)M_ * DI_ / 2;
    unsigned short* dtr_bf = (unsigned short*)ws;  ws += (size_t)M_ * DR_ / 2;
    unsigned short* wsets  = (unsigned short*)ws;  ws += SETSZ;   // set 0 + set 1
    ws += SETSZ;

    // per-set weight pointers (double-buffered: cvt for layer l+1 overlaps
    // with layer l's tail kernel)
    unsigned short* ipw_b[2], *xpw_b[2], *dtpw_b[2], *opw_b[2];
    for (int s = 0; s < 2; ++s) {
        unsigned short* base = wsets + (size_t)s * SETSZ;
        ipw_b[s]  = base;
        xpw_b[s]  = base + (size_t)2 * DI_ * D_;
        dtpw_b[s] = xpw_b[s] + (size_t)96 * DI_;
        opw_b[s]  = dtpw_b[s] + (size_t)DI_ * DR_;
    }

    // scan chunk partials alias xz: NC*B*DI*DS = 2.097M floats each.
    float* Ap = xz;
    float* Hp = xz + (size_t)NC * B_ * DI_ * DS_;

    // prepend-phase aliases (dead once the layer loop starts):
    unsigned short* pc_bf   = xi_bf;
    unsigned short* w1t_bf  = ipw_b[0];                     // [1024][768]
    unsigned short* w2t_bf  = ipw_b[0] + (size_t)D_ * PCD_; // [1024][1024]
    unsigned short* tmp1_bf = xn_bf;
    float*          tmp2    = Pbuf;   // GEMM1 partials dead by then
    float*          P2buf   = scr;    // 16*131072 floats <= 2.36M
    // out_proj bf16 partials alias xz: OPK*M*D shorts = 9.4MB << xz
    unsigned short* Pop     = (unsigned short*)xz;

    const dim3 blk(256);

    // ---- prepend embed (MFMA path): silu(pc @ w1) @ w2 ----
    prep_cvt_kernel<<<dim3(96 + 192 + 256), blk, 0, stream>>>(
        pc, pc_bf, pre_w1, w1t_bf, pre_w2, w2t_bf);
    // GEMM1: [128, 1024, K=768], split-K 12 (192 blocks), silu-reduce -> bf16
    gemm_mfma_kernel<6, 64><<<dim3(D_ / 64, 1, 12), blk, 0, stream>>>(
        pc_bf, w1t_bf, Pbuf, nullptr, B_ * P_, D_, PCD_, PCD_ / 12);
    reduce_silu_bf16_kernel<<<dim3(B_ * P_ * D_ / 256), blk, 0, stream>>>(
        Pbuf, tmp1_bf, B_ * P_ * D_, 12);
    // GEMM2: [128, 1024, K=1024], split-K 16 (256 blocks), reduce -> fp32
    gemm_mfma_kernel<6, 64><<<dim3(D_ / 64, 1, 16), blk, 0, stream>>>(
        tmp1_bf, w2t_bf, P2buf, nullptr, B_ * P_, D_, D_, D_ / 16);
    reduce_fp32_kernel<<<dim3(B_ * P_ * D_ / 256), blk, 0, stream>>>(
        P2buf, tmp2, B_ * P_ * D_, 16);
    assemble_h_kernel<<<dim3(M_ * D_ / 4 / 256), blk, 0, stream>>>(tmp2, x, h);

    // first layer's rmsnorm + layer-0 weight conversion (merged)
    rmsnorm_cvt_kernel<<<dim3(M_ + CVB), blk, 0, stream>>>(
        h, norm_w, xn_bf,
        ip_w, ipw_b[0], N_IP,
        xp_w, xpw_b[0], N_XP,
        dtp_w, dtpw_b[0], N_DTP,
        op_w, opw_b[0], N_OP);

    for (int l = 0; l < L_; ++l) {
        const int s = l & 1;
        // in_proj (MFMA, BN=64 -> 576 blocks = 2.25/CU): x -> xb, z -> szb
        gemm_mfma_kernel<7, 64><<<dim3(2 * DI_ / 64, M_ / 128, 1), blk, 0, stream>>>(
            xn_bf, ipw_b[s], (float*)xb_bf, (float*)szb_bf, M_, 2 * DI_, D_, D_);
        // conv + silu: xi_bf [m][e] (sole xi copy; scan reads it too)
        conv_silu_kernel<<<dim3(M_ / 64, DI_ / 64), blk, 0, stream>>>(
            xb_bf, conv_w + (size_t)l * DI_ * DC_, conv_b + (size_t)l * DI_,
            xi_bf);
        // x_proj (split-K MFMA) + reduce -> dtr_bf, Bc, Cc
        xproj_mfma_kernel<<<dim3(XKS, M_ / 128), blk, 0, stream>>>(
            xi_bf, xpw_b[s], Pbuf);
        xproj_reduce_kernel<<<dim3((M_ * 96 + 255) / 256), blk, 0, stream>>>(
            Pbuf, Bc, Cc, dtr_bf);
        // chunked scan, channel-per-thread, dt_proj fused (512 blocks)
        scan_chunk1_kernel<<<dim3(NC * B_ * DI_ / 256), blk, 0, stream>>>(
            dtr_bf, dtpw_b[s], dtp_b + (size_t)l * DI_, Bc, xi_bf,
            A_log + (size_t)l * DI_ * DS_, Ap, Hp);
        scan_chunk2_kernel<<<dim3(B_ * DI_ * DS_ / 256), blk, 0, stream>>>(Ap, Hp);
        scan_chunk3_kernel<<<dim3(NC * B_ * DI_ / 256), blk, 0, stream>>>(
            dtr_bf, dtpw_b[s], dtp_b + (size_t)l * DI_, Bc, Cc, xi_bf, szb_bf,
            A_log + (size_t)l * DI_ * DS_, D_param + (size_t)l * DI_, Hp, yb_bf);
        // out_proj (BN=64, split-K=OPK -> 576 blocks; BF16 partials into xz)
        gemm_mfma_kernel<8, 64><<<dim3(D_ / 64, M_ / 128, OPK), blk, 0, stream>>>(
            yb_bf, opw_b[s], (float*)Pop, nullptr, M_, D_, DI_, DI_ / OPK);
        // reduce + residual + next rmsnorm + next layer's weight cvt (merged)
        const int docvt = (l + 1 < L_);
        outproj_rmsnorm_cvt_kernel<<<dim3(M_ + (docvt ? CVB : 0)), blk, 0, stream>>>(
            Pop, h, norm_w + (size_t)((l + 1) & 3) * D_, xn_bf, l < L_ - 1,
            ip_w + (size_t)(l + 1) * 2 * DI_ * D_, ipw_b[s ^ 1], docvt ? N_IP : 0,
            xp_w + (size_t)(l + 1) * 96 * DI_, xpw_b[s ^ 1], docvt ? N_XP : 0,
            dtp_w + (size_t)(l + 1) * DI_ * DR_, dtpw_b[s ^ 1], docvt ? N_DTP : 0,
            op_w + (size_t)(l + 1) * D_ * DI_, opw_b[s ^ 1], docvt ? N_OP : 0);
    }

    final_rmsnorm_kernel<<<dim3(B_ * S_), blk, 0, stream>>>(h, fnw, out);
}